// Round 15
// baseline (240.915 us; speedup 1.0000x reference)
//
#include <hip/hip_runtime.h>

// HyperMixer fused kernel, MI355X (gfx950).
// x[B=2,S=4096,K=4,D=2048] f32, out[B,S,D] f32, W[24][8192] f32,
// scale[3], base[24]. Output = concat(y[B,S,K,D], collapsed[B,S,D]) f32.
//
// Round-15: grid-stride strip + global_load_lds prefetch pipeline.
// Evidence: r11-r14 plateau ~175us at VALUBusy 25% / HBM 33% across
// occupancies 42-61% and TOKS 2/3/4; allocator pins 52 VGPR regardless of
// __launch_bounds__ (r14: arg2=2 still 52, spilled the out-prefetch).
// -> the stall is phase-coupling: HBM idles during compute phases.
// Fix: 256 blocks (1/CU), each owns 32 tokens = 16 groups of 2.
// Pipeline per group: phaseA(g) || prefetch(g+1) in flight -> barrier
// (implicit vmcnt drain = exactly when data needed) -> convert(g+1)
// f32 stage -> f16 xh[(g+1)&1] (waves 0-3; exact-f32 sumsq) || scalar
// weights(g) (wave 7) -> barrier -> ISSUE prefetch(g+2) (zero VGPRs,
// direct HBM->LDS) -> phaseB(g). Prefetch rides over phaseB+phaseA.
// Kept validated: f16 W (conv pre-pass, L2-resident), v_dot2_f32_f16,
// scalar in-reg sinkhorn, bounded unrolls, bare __launch_bounds__.
// LDS: stage 64K + xh 2x32K + aux = ~128.5 KB -> 1 block/CU.

#define EPS 1e-6f
constexpr int D_ = 2048, KD = 8192, NOUT = 24;
constexpr int NTOK = 8192;
constexpr int TPB = 512;
constexpr int TPG = 2;                      // tokens per group
constexpr int NBLK = 256;                   // 1 block per CU
constexpr int NG = NTOK / (NBLK * TPG);     // 16 groups per block

typedef _Float16 h2 __attribute__((ext_vector_type(2)));

static __device__ __forceinline__ unsigned int pk2(float a, float b) {
    h2 h; h.x = (_Float16)a; h.y = (_Float16)b;
    return __builtin_bit_cast(unsigned int, h);
}

static __device__ __forceinline__ float dot2(unsigned int w, unsigned int x, float c) {
#if __has_builtin(__builtin_amdgcn_fdot2)
    return __builtin_amdgcn_fdot2(__builtin_bit_cast(h2, w),
                                  __builtin_bit_cast(h2, x), c, false);
#else
    h2 hw = __builtin_bit_cast(h2, w), hx = __builtin_bit_cast(h2, x);
    return c + (float)hw.x * (float)hx.x + (float)hw.y * (float)hx.y;
#endif
}

static __device__ __forceinline__ float frcp(float v) {
#if __has_builtin(__builtin_amdgcn_rcpf)
    return __builtin_amdgcn_rcpf(v);
#else
    return 1.f / v;
#endif
}

// Wh: linear f16 of W. Thread g converts 8 consecutive floats.
__global__ void conv_w_kernel(const float* __restrict__ W, unsigned int* __restrict__ Wh) {
    int g = blockIdx.x * blockDim.x + threadIdx.x;   // 24576 threads
    const float* src = W + (size_t)g * 8;
    float4 a = *reinterpret_cast<const float4*>(src);
    float4 b = *reinterpret_cast<const float4*>(src + 4);
    uint4 u;
    u.x = pk2(a.x, a.y); u.y = pk2(a.z, a.w);
    u.z = pk2(b.x, b.y); u.w = pk2(b.z, b.w);
    *reinterpret_cast<uint4*>(Wh + (size_t)g * 4) = u;
}

__global__ __launch_bounds__(TPB) void hypermix_kernel(
    const float* __restrict__ x, const float* __restrict__ outp,
    const unsigned int* __restrict__ Wh,
    const float* __restrict__ scale, const float* __restrict__ base,
    float* __restrict__ y, float* __restrict__ coll)
{
    const int t = threadIdx.x;
    const int w = t >> 6, lane = t & 63;
    const size_t tok0 = (size_t)blockIdx.x * (NG * TPG);

    __shared__ float stage[TPG * KD];            // 64 KB f32 staging (1 group)
    __shared__ unsigned int xh[2][TPG][KD / 2];  // 64 KB f16 double buffer
    __shared__ float ssred[2][4];                // sumsq partials per buffer
    __shared__ float lg[TPG][NOUT];              // raw dots, current group
    __shared__ float wts[TPG][NOUT];             // weights, current group

    // issue 8 x 16B direct HBM->LDS loads for group gr (zero VGPR cost)
    auto PREF = [&](int gr) {
        const float* gsrc = x + (tok0 + (size_t)gr * TPG) * KD;
#pragma unroll
        for (int i = 0; i < 8; ++i)
            __builtin_amdgcn_global_load_lds(
                (const __attribute__((address_space(1))) unsigned int*)(gsrc + (i * 512 + t) * 4),
                (__attribute__((address_space(3))) unsigned int*)(&stage[(i * 512 + t) * 4]),
                16, 0, 0);
    };

    // waves 0..3: stage f32 -> xh[buf] f16 + exact-f32 sumsq
    auto CONVERT = [&](int buf) {
        if (w < 4) {
            const int tk = t >> 7, cl = t & 127;
            float ss = 0.f;
#pragma unroll 4
            for (int i = 0; i < 16; ++i) {
                float4 a = *reinterpret_cast<const float4*>(&stage[tk * KD + cl * 4 + i * 512]);
                ss += a.x * a.x + a.y * a.y + a.z * a.z + a.w * a.w;
                uint2 p; p.x = pk2(a.x, a.y); p.y = pk2(a.z, a.w);
                *reinterpret_cast<uint2*>(&xh[buf][tk][cl * 2 + i * 256]) = p;
            }
#pragma unroll
            for (int m = 1; m < 64; m <<= 1) ss += __shfl_xor(ss, m, 64);
            if (lane == 0) ssred[buf][w] = ss;
        }
    };

    // wave 7 lanes 0..1: scalar per-token weights (sigmoid/softmax/sinkhorn)
    auto WEIGHTS = [&](int cur) {
        if (w == 7 && lane < TPG) {
            const int tk = lane;
            float ss = ssred[cur][2 * tk] + ssred[cur][2 * tk + 1];
            float rms = rsqrtf(ss * (1.f / 8192.f) + EPS);
            float s0 = scale[0], s1 = scale[1], s2 = scale[2];
            float l[24];
#pragma unroll
            for (int i = 0; i < 24; ++i) l[i] = lg[tk][i];
#pragma unroll
            for (int k = 0; k < 4; ++k) {
                float z0 = l[k] * rms * s0 + base[k];
                wts[tk][k] = frcp(1.f + __expf(-z0)) + EPS;
                float z1 = l[4 + k] * rms * s1 + base[4 + k];
                wts[tk][4 + k] = 2.f * frcp(1.f + __expf(-z1));
            }
            float p[16];
#pragma unroll
            for (int h = 0; h < 4; ++h) {
                float c0 = l[8 + h * 4 + 0] * rms * s2 + base[8 + h * 4 + 0];
                float c1 = l[8 + h * 4 + 1] * rms * s2 + base[8 + h * 4 + 1];
                float c2 = l[8 + h * 4 + 2] * rms * s2 + base[8 + h * 4 + 2];
                float c3 = l[8 + h * 4 + 3] * rms * s2 + base[8 + h * 4 + 3];
                float mx = fmaxf(fmaxf(c0, c1), fmaxf(c2, c3));
                float e0 = __expf(c0 - mx), e1 = __expf(c1 - mx);
                float e2 = __expf(c2 - mx), e3 = __expf(c3 - mx);
                float inv = frcp(e0 + e1 + e2 + e3);
                p[h * 4 + 0] = e0 * inv + EPS; p[h * 4 + 1] = e1 * inv + EPS;
                p[h * 4 + 2] = e2 * inv + EPS; p[h * 4 + 3] = e3 * inv + EPS;
            }
#pragma unroll
            for (int k = 0; k < 4; ++k) {
                float inv = frcp(p[k] + p[4 + k] + p[8 + k] + p[12 + k] + EPS);
                p[k] *= inv; p[4 + k] *= inv; p[8 + k] *= inv; p[12 + k] *= inv;
            }
#pragma unroll 1
            for (int itn = 0; itn < 19; ++itn) {
#pragma unroll
                for (int h = 0; h < 4; ++h) {
                    float inv = frcp(p[h * 4] + p[h * 4 + 1] + p[h * 4 + 2] + p[h * 4 + 3] + EPS);
                    p[h * 4] *= inv; p[h * 4 + 1] *= inv; p[h * 4 + 2] *= inv; p[h * 4 + 3] *= inv;
                }
#pragma unroll
                for (int k = 0; k < 4; ++k) {
                    float inv = frcp(p[k] + p[4 + k] + p[8 + k] + p[12 + k] + EPS);
                    p[k] *= inv; p[4 + k] *= inv; p[8 + k] *= inv; p[12 + k] *= inv;
                }
            }
#pragma unroll
            for (int i = 0; i < 16; ++i) wts[tk][8 + i] = p[i];
        }
    };

    // all 512 threads: one token's outputs (t*4 covers D exactly)
    auto PHB = [&](int tt, int cur, const float4& ov, size_t gtok) {
        float pre[4], post[4], cmb[4][4];
#pragma unroll
        for (int k = 0; k < 4; ++k) { pre[k] = wts[tt][k]; post[k] = wts[tt][4 + k]; }
#pragma unroll
        for (int h = 0; h < 4; ++h)
#pragma unroll
            for (int k = 0; k < 4; ++k) cmb[h][k] = wts[tt][8 + h * 4 + k];
        const int d = t * 4;
        float xk[4][4];
#pragma unroll
        for (int k = 0; k < 4; ++k) {
            uint2 pq = *reinterpret_cast<const uint2*>(&xh[cur][tt][k * 1024 + t * 2]);
            h2 h0 = __builtin_bit_cast(h2, pq.x), h1 = __builtin_bit_cast(h2, pq.y);
            xk[k][0] = (float)h0.x; xk[k][1] = (float)h0.y;
            xk[k][2] = (float)h1.x; xk[k][3] = (float)h1.y;
        }
        float* yb = y + gtok * KD;
        float* cb = coll + gtok * D_;
        float cv[4], yv[4];
#pragma unroll
        for (int e = 0; e < 4; ++e)
            cv[e] = pre[0] * xk[0][e] + pre[1] * xk[1][e]
                  + pre[2] * xk[2][e] + pre[3] * xk[3][e];
        *reinterpret_cast<float4*>(cb + d) = make_float4(cv[0], cv[1], cv[2], cv[3]);
        const float oe[4] = {ov.x, ov.y, ov.z, ov.w};
#pragma unroll
        for (int h = 0; h < 4; ++h) {
#pragma unroll
            for (int e = 0; e < 4; ++e)
                yv[e] = post[h] * oe[e] + cmb[h][0] * xk[0][e] + cmb[h][1] * xk[1][e]
                      + cmb[h][2] * xk[2][e] + cmb[h][3] * xk[3][e];
            *reinterpret_cast<float4*>(yb + h * D_ + d) =
                make_float4(yv[0], yv[1], yv[2], yv[3]);
        }
    };

    // ---- prologue: fill group 0, start group 1 ----
    PREF(0);
    __syncthreads();          // implicit vmcnt drain -> stage(0) ready
    CONVERT(0);
    __syncthreads();
    PREF(1);

    // ---- steady-state pipeline over 16 groups ----
#pragma unroll 1
    for (int g = 0; g < NG; ++g) {
        const int cur = g & 1;
        const size_t gt = tok0 + (size_t)g * TPG;
        float4 ovr0 = *reinterpret_cast<const float4*>(outp + gt * D_ + t * 4);
        float4 ovr1 = *reinterpret_cast<const float4*>(outp + (gt + 1) * D_ + t * 4);

        // phase A: wave w -> rows 3w..3w+2, both tokens, from xh[cur]
        {
            const int r0 = w * 3;
            float acc[3][2] = {};
#pragma unroll 2
            for (int it = 0; it < 16; ++it) {
                const int gi4 = (it * 64 + lane) * 4;
                uint4 xa = *reinterpret_cast<const uint4*>(&xh[cur][0][gi4]);
                uint4 xb = *reinterpret_cast<const uint4*>(&xh[cur][1][gi4]);
#pragma unroll
                for (int j = 0; j < 3; ++j) {
                    uint4 wv = *reinterpret_cast<const uint4*>(
                        Wh + (size_t)(r0 + j) * 4096 + gi4);
                    acc[j][0] = dot2(wv.x, xa.x, acc[j][0]);
                    acc[j][0] = dot2(wv.y, xa.y, acc[j][0]);
                    acc[j][0] = dot2(wv.z, xa.z, acc[j][0]);
                    acc[j][0] = dot2(wv.w, xa.w, acc[j][0]);
                    acc[j][1] = dot2(wv.x, xb.x, acc[j][1]);
                    acc[j][1] = dot2(wv.y, xb.y, acc[j][1]);
                    acc[j][1] = dot2(wv.z, xb.z, acc[j][1]);
                    acc[j][1] = dot2(wv.w, xb.w, acc[j][1]);
                }
            }
#pragma unroll
            for (int j = 0; j < 3; ++j) {
                float v0 = acc[j][0], v1 = acc[j][1];
#pragma unroll
                for (int m = 1; m < 64; m <<= 1) {
                    v0 += __shfl_xor(v0, m, 64);
                    v1 += __shfl_xor(v1, m, 64);
                }
                if (lane == 0) { lg[0][r0 + j] = v0; lg[1][r0 + j] = v1; }
            }
        }
        __syncthreads();       // drains prefetch(g+1): stage ready; lg visible

        if (g + 1 < NG) CONVERT(cur ^ 1);   // waves 0-3
        WEIGHTS(cur);                        // wave 7, lanes 0-1
        __syncthreads();

        if (g + 2 < NG) PREF(g + 2);        // in flight across phaseB + next phaseA

        PHB(0, cur, ovr0, gt);
        PHB(1, cur, ovr1, gt + 1);
    }
}

extern "C" void kernel_launch(void* const* d_in, const int* in_sizes, int n_in,
                              void* d_out, int out_size, void* d_ws, size_t ws_size,
                              hipStream_t stream) {
    const float* x     = (const float*)d_in[0];
    const float* outp  = (const float*)d_in[1];
    const float* W     = (const float*)d_in[2];
    const float* scale = (const float*)d_in[3];
    const float* base  = (const float*)d_in[4];
    float* y    = (float*)d_out;
    float* coll = y + (size_t)NTOK * KD;   // 67108864

    unsigned int* Wh = (unsigned int*)d_ws;     // 384 KB f16 (ws is larger)
    conv_w_kernel<<<NOUT * KD / 8 / 256, 256, 0, stream>>>(W, Wh);
    hypermix_kernel<<<NBLK, TPB, 0, stream>>>(x, outp, Wh, scale, base, y, coll);
}

// Round 16
// 217.931 us; speedup vs baseline: 1.1055x; 1.1055x over previous
//
#include <hip/hip_runtime.h>

// HyperMixer, MI355X (gfx950) — round 16: 4-kernel stream split.
// x[8192,4,2048] f32, out[8192,2048] f32, W[24][8192] f32 -> y + collapsed.
//
// r10-r15 evidence: fused single-kernel variants plateau 175-240us with
// VALUBusy<=27%, HBM<=33%; per-block serial path ~50us regardless of
// occupancy (r12: 42->61% occ, no change) or pipelining (r13/r14 null,
// allocator pins 52 VGPR; r15 deep pipeline regressed at 1 block/CU).
// Split: (1) logits kernel = proven r11 phase0+phaseA, ends at 25-float
// store/token -> blocks retire with no serial tail; (2) weights kernel =
// scalar sinkhorn, one THREAD per token (8192-way parallel, removes the
// 4-lane serial bubble); (3) combine kernel = pure streaming (fill-kernel
// shaped, 6.8 TB/s measured ceiling), f32 x (better accuracy than f16
// phase-B), x hot in L3 from (1). ws: 384KB Wh + 1MB lg/wts.

#define EPS 1e-6f
constexpr int D_ = 2048, KD = 8192, NOUT = 24;
constexpr int NTOK = 8192;
constexpr int TPB = 512;
constexpr int TOKS = 4;
constexpr int NBLK1 = NTOK / TOKS;          // 2048

typedef _Float16 h2 __attribute__((ext_vector_type(2)));

static __device__ __forceinline__ unsigned int pk2(float a, float b) {
    h2 h; h.x = (_Float16)a; h.y = (_Float16)b;
    return __builtin_bit_cast(unsigned int, h);
}

static __device__ __forceinline__ float dot2(unsigned int w, unsigned int x, float c) {
#if __has_builtin(__builtin_amdgcn_fdot2)
    return __builtin_amdgcn_fdot2(__builtin_bit_cast(h2, w),
                                  __builtin_bit_cast(h2, x), c, false);
#else
    h2 hw = __builtin_bit_cast(h2, w), hx = __builtin_bit_cast(h2, x);
    return c + (float)hw.x * (float)hx.x + (float)hw.y * (float)hx.y;
#endif
}

static __device__ __forceinline__ float frcp(float v) {
#if __has_builtin(__builtin_amdgcn_rcpf)
    return __builtin_amdgcn_rcpf(v);
#else
    return 1.f / v;
#endif
}

// ---- kernel 1: W f32 -> f16 (linear) ----
__global__ void conv_w_kernel(const float* __restrict__ W, unsigned int* __restrict__ Wh) {
    int g = blockIdx.x * blockDim.x + threadIdx.x;   // 24576 threads
    const float* src = W + (size_t)g * 8;
    float4 a = *reinterpret_cast<const float4*>(src);
    float4 b = *reinterpret_cast<const float4*>(src + 4);
    uint4 u;
    u.x = pk2(a.x, a.y); u.y = pk2(a.z, a.w);
    u.z = pk2(b.x, b.y); u.w = pk2(b.z, b.w);
    *reinterpret_cast<uint4*>(Wh + (size_t)g * 4) = u;
}

// ---- kernel 2: logits. lgw[tok*32 + 0..23] = raw dots, [24] = sumsq ----
__global__ __launch_bounds__(TPB) void logits_kernel(
    const float* __restrict__ x, const unsigned int* __restrict__ Wh,
    float* __restrict__ lgw)
{
    const int t = threadIdx.x;
    const int w = t >> 6, lane = t & 63;
    const int tk4 = t >> 7, t7 = t & 127;
    const size_t gt0 = (size_t)blockIdx.x * TOKS;

    __shared__ unsigned int xh[TOKS][KD / 2];  // packed f16 x, 64 KB
    __shared__ float ssred[8];                 // per-wave sumsq partials

    // phase 0 (r11-proven): 128 threads per token, 16 float4 each
    {
        const float* xb = x + (gt0 + tk4) * KD + t7 * 4;
        float ss = 0.f;
#pragma unroll 2
        for (int i = 0; i < 16; ++i) {
            float4 v = *reinterpret_cast<const float4*>(xb + i * 512);
            ss += v.x * v.x + v.y * v.y + v.z * v.z + v.w * v.w;
            uint2 p; p.x = pk2(v.x, v.y); p.y = pk2(v.z, v.w);
            *reinterpret_cast<uint2*>(&xh[tk4][i * 256 + t7 * 2]) = p;
        }
#pragma unroll
        for (int m = 1; m < 64; m <<= 1) ss += __shfl_xor(ss, m, 64);
        if (lane == 0) ssred[w] = ss;
    }
    __syncthreads();

    if (t < TOKS)
        lgw[(gt0 + t) * 32 + 24] = ssred[2 * t] + ssred[2 * t + 1];

    // phase A (r11-proven): wave w -> rows 3w..3w+2, all 4 tokens
    {
        const int r0 = w * 3;
        float acc[3][4];
#pragma unroll
        for (int j = 0; j < 3; ++j)
#pragma unroll
            for (int tt = 0; tt < 4; ++tt) acc[j][tt] = 0.f;

#pragma unroll 2
        for (int it = 0; it < 16; ++it) {
            const int gi = it * 64 + lane;
            uint4 xv0 = *reinterpret_cast<const uint4*>(&xh[0][gi * 4]);
            uint4 xv1 = *reinterpret_cast<const uint4*>(&xh[1][gi * 4]);
            uint4 xv2 = *reinterpret_cast<const uint4*>(&xh[2][gi * 4]);
            uint4 xv3 = *reinterpret_cast<const uint4*>(&xh[3][gi * 4]);
#pragma unroll
            for (int j = 0; j < 3; ++j) {
                uint4 wv = *reinterpret_cast<const uint4*>(
                    Wh + ((size_t)(r0 + j) * 4096 + gi * 4));
                acc[j][0] = dot2(wv.x, xv0.x, acc[j][0]);
                acc[j][0] = dot2(wv.y, xv0.y, acc[j][0]);
                acc[j][0] = dot2(wv.z, xv0.z, acc[j][0]);
                acc[j][0] = dot2(wv.w, xv0.w, acc[j][0]);
                acc[j][1] = dot2(wv.x, xv1.x, acc[j][1]);
                acc[j][1] = dot2(wv.y, xv1.y, acc[j][1]);
                acc[j][1] = dot2(wv.z, xv1.z, acc[j][1]);
                acc[j][1] = dot2(wv.w, xv1.w, acc[j][1]);
                acc[j][2] = dot2(wv.x, xv2.x, acc[j][2]);
                acc[j][2] = dot2(wv.y, xv2.y, acc[j][2]);
                acc[j][2] = dot2(wv.z, xv2.z, acc[j][2]);
                acc[j][2] = dot2(wv.w, xv2.w, acc[j][2]);
                acc[j][3] = dot2(wv.x, xv3.x, acc[j][3]);
                acc[j][3] = dot2(wv.y, xv3.y, acc[j][3]);
                acc[j][3] = dot2(wv.z, xv3.z, acc[j][3]);
                acc[j][3] = dot2(wv.w, xv3.w, acc[j][3]);
            }
        }
#pragma unroll
        for (int j = 0; j < 3; ++j)
#pragma unroll
            for (int tt = 0; tt < 4; ++tt) {
                float v = acc[j][tt];
#pragma unroll
                for (int m = 1; m < 64; m <<= 1) v += __shfl_xor(v, m, 64);
                if (lane == 0) lgw[(gt0 + tt) * 32 + r0 + j] = v;
            }
    }
}

// ---- kernel 3: weights. one THREAD per token, scalar sinkhorn in regs ----
__global__ __launch_bounds__(256) void weights_kernel(
    float* __restrict__ lgw,
    const float* __restrict__ scale, const float* __restrict__ base)
{
    const int tok = blockIdx.x * 256 + threadIdx.x;
    if (tok >= NTOK) return;
    float l[25];
#pragma unroll
    for (int i = 0; i < 25; ++i) l[i] = lgw[(size_t)tok * 32 + i];
    float rms = rsqrtf(l[24] * (1.f / 8192.f) + EPS);
    float s0 = scale[0], s1 = scale[1], s2 = scale[2];
    float o[8];
#pragma unroll
    for (int k = 0; k < 4; ++k) {
        float z0 = l[k] * rms * s0 + base[k];
        o[k] = frcp(1.f + __expf(-z0)) + EPS;
        float z1 = l[4 + k] * rms * s1 + base[4 + k];
        o[4 + k] = 2.f * frcp(1.f + __expf(-z1));
    }
    float p[16];
#pragma unroll
    for (int h = 0; h < 4; ++h) {
        float c0 = l[8 + h * 4 + 0] * rms * s2 + base[8 + h * 4 + 0];
        float c1 = l[8 + h * 4 + 1] * rms * s2 + base[8 + h * 4 + 1];
        float c2 = l[8 + h * 4 + 2] * rms * s2 + base[8 + h * 4 + 2];
        float c3 = l[8 + h * 4 + 3] * rms * s2 + base[8 + h * 4 + 3];
        float mx = fmaxf(fmaxf(c0, c1), fmaxf(c2, c3));
        float e0 = __expf(c0 - mx), e1 = __expf(c1 - mx);
        float e2 = __expf(c2 - mx), e3 = __expf(c3 - mx);
        float inv = frcp(e0 + e1 + e2 + e3);
        p[h * 4 + 0] = e0 * inv + EPS; p[h * 4 + 1] = e1 * inv + EPS;
        p[h * 4 + 2] = e2 * inv + EPS; p[h * 4 + 3] = e3 * inv + EPS;
    }
#pragma unroll
    for (int k = 0; k < 4; ++k) {
        float inv = frcp(p[k] + p[4 + k] + p[8 + k] + p[12 + k] + EPS);
        p[k] *= inv; p[4 + k] *= inv; p[8 + k] *= inv; p[12 + k] *= inv;
    }
#pragma unroll 1
    for (int itn = 0; itn < 19; ++itn) {
#pragma unroll
        for (int h = 0; h < 4; ++h) {
            float inv = frcp(p[h * 4] + p[h * 4 + 1] + p[h * 4 + 2] + p[h * 4 + 3] + EPS);
            p[h * 4] *= inv; p[h * 4 + 1] *= inv; p[h * 4 + 2] *= inv; p[h * 4 + 3] *= inv;
        }
#pragma unroll
        for (int k = 0; k < 4; ++k) {
            float inv = frcp(p[k] + p[4 + k] + p[8 + k] + p[12 + k] + EPS);
            p[k] *= inv; p[4 + k] *= inv; p[8 + k] *= inv; p[12 + k] *= inv;
        }
    }
    // write weights in place: [0..3]=pre, [4..7]=post, [8..23]=comb
#pragma unroll
    for (int i = 0; i < 8; ++i) lgw[(size_t)tok * 32 + i] = o[i];
#pragma unroll
    for (int i = 0; i < 16; ++i) lgw[(size_t)tok * 32 + 8 + i] = p[i];
}

// ---- kernel 4: combine. one token per block, pure streaming, f32 x ----
__global__ __launch_bounds__(TPB) void combine_kernel(
    const float* __restrict__ x, const float* __restrict__ outp,
    const float* __restrict__ lgw,
    float* __restrict__ y, float* __restrict__ coll)
{
    const int t = threadIdx.x;
    const size_t tok = blockIdx.x;

    __shared__ float wl[NOUT];
    if (t < NOUT) wl[t] = lgw[tok * 32 + t];
    __syncthreads();

    const int d = t * 4;
    const float* xb = x + tok * KD + d;
    float4 xk[4];
#pragma unroll
    for (int k = 0; k < 4; ++k)
        xk[k] = *reinterpret_cast<const float4*>(xb + k * D_);
    float4 ov = *reinterpret_cast<const float4*>(outp + tok * D_ + d);

    float pre[4], post[4], cmb[4][4];
#pragma unroll
    for (int k = 0; k < 4; ++k) { pre[k] = wl[k]; post[k] = wl[4 + k]; }
#pragma unroll
    for (int h = 0; h < 4; ++h)
#pragma unroll
        for (int k = 0; k < 4; ++k) cmb[h][k] = wl[8 + h * 4 + k];

    const float xe[4][4] = {
        {xk[0].x, xk[0].y, xk[0].z, xk[0].w},
        {xk[1].x, xk[1].y, xk[1].z, xk[1].w},
        {xk[2].x, xk[2].y, xk[2].z, xk[2].w},
        {xk[3].x, xk[3].y, xk[3].z, xk[3].w}};
    const float oe[4] = {ov.x, ov.y, ov.z, ov.w};

    float cv[4];
#pragma unroll
    for (int e = 0; e < 4; ++e)
        cv[e] = pre[0] * xe[0][e] + pre[1] * xe[1][e]
              + pre[2] * xe[2][e] + pre[3] * xe[3][e];
    *reinterpret_cast<float4*>(coll + tok * D_ + d) =
        make_float4(cv[0], cv[1], cv[2], cv[3]);

    float* yb = y + tok * KD + d;
#pragma unroll
    for (int h = 0; h < 4; ++h) {
        float yv[4];
#pragma unroll
        for (int e = 0; e < 4; ++e)
            yv[e] = post[h] * oe[e] + cmb[h][0] * xe[0][e] + cmb[h][1] * xe[1][e]
                  + cmb[h][2] * xe[2][e] + cmb[h][3] * xe[3][e];
        *reinterpret_cast<float4*>(yb + h * D_) =
            make_float4(yv[0], yv[1], yv[2], yv[3]);
    }
}

extern "C" void kernel_launch(void* const* d_in, const int* in_sizes, int n_in,
                              void* d_out, int out_size, void* d_ws, size_t ws_size,
                              hipStream_t stream) {
    const float* x     = (const float*)d_in[0];
    const float* outp  = (const float*)d_in[1];
    const float* W     = (const float*)d_in[2];
    const float* scale = (const float*)d_in[3];
    const float* base  = (const float*)d_in[4];
    float* y    = (float*)d_out;
    float* coll = y + (size_t)NTOK * KD;   // 67108864

    // ws layout: [0, 384KB) = Wh f16; [384KB, +1MB) = lgw (32 f32/token)
    unsigned int* Wh = (unsigned int*)d_ws;
    float* lgw = (float*)((char*)d_ws + (size_t)NOUT * KD * 2);

    conv_w_kernel<<<NOUT * KD / 8 / 256, 256, 0, stream>>>(W, Wh);
    logits_kernel<<<NBLK1, TPB, 0, stream>>>(x, Wh, lgw);
    weights_kernel<<<NTOK / 256, 256, 0, stream>>>(lgw, scale, base);
    combine_kernel<<<NTOK, TPB, 0, stream>>>(x, outp, lgw, y, coll);
}

// Round 17
// 180.550 us; speedup vs baseline: 1.3343x; 1.2070x over previous
//
#include <hip/hip_runtime.h>

// HyperMixer fused kernel, MI355X (gfx950) — round 17.
// x[8192,4,2048] f32, out[8192,2048] f32, W[24][8192] f32 -> y + collapsed.
//
// Theory from r10-r16: the ~175us plateau is phase-0 MLP. Streaming
// 6.3 TB/s needs ~6 outstanding 16B loads/lane (2.3 KB/SIMD in flight at
// ~900cyc HBM latency); unroll-2 gave 2. r16 split showed combine's x
// re-read erases any gain (218us) -> stay fused, minimum traffic 640 MB.
// Fix: issue ALL 15 independent loads (12 x + 3 out float4) before any
// convert; stage out in LDS so phase B is LDS+write-stream only.
// Kept verbatim (proven): TOKS=3 (r12), phase-A unroll-2 + shared-W
// across tokens (r11), scalar 3-lane in-reg sinkhorn (r13), f16 W conv
// pre-pass + v_dot2_f32_f16 (r7+), bare __launch_bounds__ (r7/r8: arg2
// caps VGPR), no reg-resident x across barriers (r5), WRITE_SIZE ==
// 327,680 KB is the no-spill tripwire.

#define EPS 1e-6f
constexpr int D_ = 2048, KD = 8192, NOUT = 24;
constexpr int NTOK = 8192;
constexpr int TPB = 512;
constexpr int TOKS = 3;
constexpr int NBLK = (NTOK + TOKS - 1) / TOKS;   // 2731

typedef _Float16 h2 __attribute__((ext_vector_type(2)));

static __device__ __forceinline__ unsigned int pk2(float a, float b) {
    h2 h; h.x = (_Float16)a; h.y = (_Float16)b;
    return __builtin_bit_cast(unsigned int, h);
}

static __device__ __forceinline__ float dot2(unsigned int w, unsigned int x, float c) {
#if __has_builtin(__builtin_amdgcn_fdot2)
    return __builtin_amdgcn_fdot2(__builtin_bit_cast(h2, w),
                                  __builtin_bit_cast(h2, x), c, false);
#else
    h2 hw = __builtin_bit_cast(h2, w), hx = __builtin_bit_cast(h2, x);
    return c + (float)hw.x * (float)hx.x + (float)hw.y * (float)hx.y;
#endif
}

static __device__ __forceinline__ float frcp(float v) {
#if __has_builtin(__builtin_amdgcn_rcpf)
    return __builtin_amdgcn_rcpf(v);
#else
    return 1.f / v;
#endif
}

// Wh: linear f16 of W. Thread g converts 8 consecutive floats.
__global__ void conv_w_kernel(const float* __restrict__ W, unsigned int* __restrict__ Wh) {
    int g = blockIdx.x * blockDim.x + threadIdx.x;   // 24576 threads
    const float* src = W + (size_t)g * 8;
    float4 a = *reinterpret_cast<const float4*>(src);
    float4 b = *reinterpret_cast<const float4*>(src + 4);
    uint4 u;
    u.x = pk2(a.x, a.y); u.y = pk2(a.z, a.w);
    u.z = pk2(b.x, b.y); u.w = pk2(b.z, b.w);
    *reinterpret_cast<uint4*>(Wh + (size_t)g * 4) = u;
}

__global__ __launch_bounds__(TPB) void hypermix_kernel(
    const float* __restrict__ x, const float* __restrict__ outp,
    const unsigned int* __restrict__ Wh,
    const float* __restrict__ scale, const float* __restrict__ base,
    float* __restrict__ y, float* __restrict__ coll)
{
    const int t = threadIdx.x;
    const int w = t >> 6, lane = t & 63;
    const size_t gt0 = (size_t)blockIdx.x * TOKS;
    const size_t tks0 = gt0;
    const size_t tks1 = (gt0 + 1 < NTOK) ? gt0 + 1 : NTOK - 1;   // clamped reads
    const size_t tks2 = (gt0 + 2 < NTOK) ? gt0 + 2 : NTOK - 1;

    __shared__ unsigned int xh[TOKS][KD / 2];  // packed f16 x, 48 KB
    __shared__ float os[TOKS][D_];             // staged out, 24 KB
    __shared__ float ssred[TOKS][8];           // per-wave sumsq partials
    __shared__ float lg[TOKS][24];             // raw dot products
    __shared__ float wts[TOKS][24];            // 0..3 pre, 4..7 post, 8..23 comb

    // ---- phase 0: issue ALL 15 loads (12 x + 3 out), then convert ----
    {
        const float* xb0 = x + tks0 * KD + t * 4;
        const float* xb1 = x + tks1 * KD + t * 4;
        const float* xb2 = x + tks2 * KD + t * 4;
        float4 a0[4], a1[4], a2[4];
#pragma unroll
        for (int i = 0; i < 4; ++i) a0[i] = *reinterpret_cast<const float4*>(xb0 + i * 2048);
#pragma unroll
        for (int i = 0; i < 4; ++i) a1[i] = *reinterpret_cast<const float4*>(xb1 + i * 2048);
#pragma unroll
        for (int i = 0; i < 4; ++i) a2[i] = *reinterpret_cast<const float4*>(xb2 + i * 2048);
        float4 o0 = *reinterpret_cast<const float4*>(outp + tks0 * D_ + t * 4);
        float4 o1 = *reinterpret_cast<const float4*>(outp + tks1 * D_ + t * 4);
        float4 o2 = *reinterpret_cast<const float4*>(outp + tks2 * D_ + t * 4);

        float ss0 = 0.f, ss1 = 0.f, ss2 = 0.f;
#pragma unroll
        for (int i = 0; i < 4; ++i) {
            ss0 += a0[i].x * a0[i].x + a0[i].y * a0[i].y + a0[i].z * a0[i].z + a0[i].w * a0[i].w;
            uint2 p; p.x = pk2(a0[i].x, a0[i].y); p.y = pk2(a0[i].z, a0[i].w);
            *reinterpret_cast<uint2*>(&xh[0][i * 1024 + t * 2]) = p;
        }
#pragma unroll
        for (int i = 0; i < 4; ++i) {
            ss1 += a1[i].x * a1[i].x + a1[i].y * a1[i].y + a1[i].z * a1[i].z + a1[i].w * a1[i].w;
            uint2 p; p.x = pk2(a1[i].x, a1[i].y); p.y = pk2(a1[i].z, a1[i].w);
            *reinterpret_cast<uint2*>(&xh[1][i * 1024 + t * 2]) = p;
        }
#pragma unroll
        for (int i = 0; i < 4; ++i) {
            ss2 += a2[i].x * a2[i].x + a2[i].y * a2[i].y + a2[i].z * a2[i].z + a2[i].w * a2[i].w;
            uint2 p; p.x = pk2(a2[i].x, a2[i].y); p.y = pk2(a2[i].z, a2[i].w);
            *reinterpret_cast<uint2*>(&xh[2][i * 1024 + t * 2]) = p;
        }
        *reinterpret_cast<float4*>(&os[0][t * 4]) = o0;
        *reinterpret_cast<float4*>(&os[1][t * 4]) = o1;
        *reinterpret_cast<float4*>(&os[2][t * 4]) = o2;

        // interleaved butterfly chains
#pragma unroll
        for (int m = 1; m < 64; m <<= 1) {
            ss0 += __shfl_xor(ss0, m, 64);
            ss1 += __shfl_xor(ss1, m, 64);
            ss2 += __shfl_xor(ss2, m, 64);
        }
        if (lane == 0) { ssred[0][w] = ss0; ssred[1][w] = ss1; ssred[2][w] = ss2; }
    }
    __syncthreads();

    // ---- phase A: wave w -> rows 3w..3w+2, all 3 tokens (shared W load) ----
    {
        const int r0 = w * 3;
        float acc[3][TOKS];
#pragma unroll
        for (int j = 0; j < 3; ++j)
#pragma unroll
            for (int tt = 0; tt < TOKS; ++tt) acc[j][tt] = 0.f;

#pragma unroll 2
        for (int it = 0; it < 16; ++it) {
            const int gi = it * 64 + lane;          // uint4 group = 8 f16
            uint4 xv0 = *reinterpret_cast<const uint4*>(&xh[0][gi * 4]);
            uint4 xv1 = *reinterpret_cast<const uint4*>(&xh[1][gi * 4]);
            uint4 xv2 = *reinterpret_cast<const uint4*>(&xh[2][gi * 4]);
#pragma unroll
            for (int j = 0; j < 3; ++j) {
                uint4 wv = *reinterpret_cast<const uint4*>(
                    Wh + ((size_t)(r0 + j) * 4096 + gi * 4));
                acc[j][0] = dot2(wv.x, xv0.x, acc[j][0]);
                acc[j][0] = dot2(wv.y, xv0.y, acc[j][0]);
                acc[j][0] = dot2(wv.z, xv0.z, acc[j][0]);
                acc[j][0] = dot2(wv.w, xv0.w, acc[j][0]);
                acc[j][1] = dot2(wv.x, xv1.x, acc[j][1]);
                acc[j][1] = dot2(wv.y, xv1.y, acc[j][1]);
                acc[j][1] = dot2(wv.z, xv1.z, acc[j][1]);
                acc[j][1] = dot2(wv.w, xv1.w, acc[j][1]);
                acc[j][2] = dot2(wv.x, xv2.x, acc[j][2]);
                acc[j][2] = dot2(wv.y, xv2.y, acc[j][2]);
                acc[j][2] = dot2(wv.z, xv2.z, acc[j][2]);
                acc[j][2] = dot2(wv.w, xv2.w, acc[j][2]);
            }
        }
#pragma unroll
        for (int j = 0; j < 3; ++j)
#pragma unroll
            for (int tt = 0; tt < TOKS; ++tt) {
                float v = acc[j][tt];
#pragma unroll
                for (int m = 1; m < 64; m <<= 1) v += __shfl_xor(v, m, 64);
                if (lane == 0) lg[tt][r0 + j] = v;
            }
    }
    __syncthreads();

    // ---- weights: scalar per-token (3 lanes), sinkhorn fully in regs ----
    if (t < TOKS && gt0 + t < NTOK) {
        float ss = ssred[t][0] + ssred[t][1] + ssred[t][2] + ssred[t][3]
                 + ssred[t][4] + ssred[t][5] + ssred[t][6] + ssred[t][7];
        float rms = rsqrtf(ss * (1.f / 8192.f) + EPS);
        float s0 = scale[0], s1 = scale[1], s2 = scale[2];
        float l[24];
#pragma unroll
        for (int i = 0; i < 24; ++i) l[i] = lg[t][i];
#pragma unroll
        for (int k = 0; k < 4; ++k) {
            float z0 = l[k] * rms * s0 + base[k];
            wts[t][k] = frcp(1.f + __expf(-z0)) + EPS;
            float z1 = l[4 + k] * rms * s1 + base[4 + k];
            wts[t][4 + k] = 2.f * frcp(1.f + __expf(-z1));
        }
        float p[16];
#pragma unroll
        for (int h = 0; h < 4; ++h) {
            float c0 = l[8 + h * 4 + 0] * rms * s2 + base[8 + h * 4 + 0];
            float c1 = l[8 + h * 4 + 1] * rms * s2 + base[8 + h * 4 + 1];
            float c2 = l[8 + h * 4 + 2] * rms * s2 + base[8 + h * 4 + 2];
            float c3 = l[8 + h * 4 + 3] * rms * s2 + base[8 + h * 4 + 3];
            float mx = fmaxf(fmaxf(c0, c1), fmaxf(c2, c3));
            float e0 = __expf(c0 - mx), e1 = __expf(c1 - mx);
            float e2 = __expf(c2 - mx), e3 = __expf(c3 - mx);
            float inv = frcp(e0 + e1 + e2 + e3);
            p[h * 4 + 0] = e0 * inv + EPS; p[h * 4 + 1] = e1 * inv + EPS;
            p[h * 4 + 2] = e2 * inv + EPS; p[h * 4 + 3] = e3 * inv + EPS;
        }
#pragma unroll
        for (int k = 0; k < 4; ++k) {
            float inv = frcp(p[k] + p[4 + k] + p[8 + k] + p[12 + k] + EPS);
            p[k] *= inv; p[4 + k] *= inv; p[8 + k] *= inv; p[12 + k] *= inv;
        }
#pragma unroll 1
        for (int itn = 0; itn < 19; ++itn) {
#pragma unroll
            for (int h = 0; h < 4; ++h) {
                float inv = frcp(p[h * 4] + p[h * 4 + 1] + p[h * 4 + 2] + p[h * 4 + 3] + EPS);
                p[h * 4] *= inv; p[h * 4 + 1] *= inv; p[h * 4 + 2] *= inv; p[h * 4 + 3] *= inv;
            }
#pragma unroll
            for (int k = 0; k < 4; ++k) {
                float inv = frcp(p[k] + p[4 + k] + p[8 + k] + p[12 + k] + EPS);
                p[k] *= inv; p[4 + k] *= inv; p[8 + k] *= inv; p[12 + k] *= inv;
            }
        }
#pragma unroll
        for (int i = 0; i < 16; ++i) wts[t][8 + i] = p[i];
    }
    __syncthreads();

    // ---- phase B: per token, all 512 threads; out from LDS; pure writes ----
#pragma unroll 1
    for (int tt = 0; tt < TOKS; ++tt) {
        if (gt0 + tt >= NTOK) continue;
        float pre[4], post[4], cmb[4][4];
#pragma unroll
        for (int k = 0; k < 4; ++k) { pre[k] = wts[tt][k]; post[k] = wts[tt][4 + k]; }
#pragma unroll
        for (int h = 0; h < 4; ++h)
#pragma unroll
            for (int k = 0; k < 4; ++k) cmb[h][k] = wts[tt][8 + h * 4 + k];

        const int d = t * 4;
        float xk[4][4];
#pragma unroll
        for (int k = 0; k < 4; ++k) {
            uint2 pq = *reinterpret_cast<const uint2*>(&xh[tt][k * 1024 + t * 2]);
            h2 h0 = __builtin_bit_cast(h2, pq.x), h1 = __builtin_bit_cast(h2, pq.y);
            xk[k][0] = (float)h0.x; xk[k][1] = (float)h0.y;
            xk[k][2] = (float)h1.x; xk[k][3] = (float)h1.y;
        }
        float4 ov = *reinterpret_cast<const float4*>(&os[tt][t * 4]);
        float* yb = y + (gt0 + tt) * KD;
        float* cb = coll + (gt0 + tt) * D_;
        float cv[4], yv[4];
#pragma unroll
        for (int e = 0; e < 4; ++e)
            cv[e] = pre[0] * xk[0][e] + pre[1] * xk[1][e]
                  + pre[2] * xk[2][e] + pre[3] * xk[3][e];
        *reinterpret_cast<float4*>(cb + d) = make_float4(cv[0], cv[1], cv[2], cv[3]);
        const float oe[4] = {ov.x, ov.y, ov.z, ov.w};
#pragma unroll
        for (int h = 0; h < 4; ++h) {
#pragma unroll
            for (int e = 0; e < 4; ++e)
                yv[e] = post[h] * oe[e] + cmb[h][0] * xk[0][e] + cmb[h][1] * xk[1][e]
                      + cmb[h][2] * xk[2][e] + cmb[h][3] * xk[3][e];
            *reinterpret_cast<float4*>(yb + h * D_ + d) =
                make_float4(yv[0], yv[1], yv[2], yv[3]);
        }
    }
}

extern "C" void kernel_launch(void* const* d_in, const int* in_sizes, int n_in,
                              void* d_out, int out_size, void* d_ws, size_t ws_size,
                              hipStream_t stream) {
    const float* x     = (const float*)d_in[0];
    const float* outp  = (const float*)d_in[1];
    const float* W     = (const float*)d_in[2];
    const float* scale = (const float*)d_in[3];
    const float* base  = (const float*)d_in[4];
    float* y    = (float*)d_out;
    float* coll = y + (size_t)NTOK * KD;   // 67108864

    unsigned int* Wh = (unsigned int*)d_ws;     // 384 KB f16 (ws is larger)
    conv_w_kernel<<<NOUT * KD / 8 / 256, 256, 0, stream>>>(W, Wh);
    hypermix_kernel<<<NBLK, TPB, 0, stream>>>(x, outp, Wh, scale, base, y, coll);
}